// Round 4
// baseline (307.737 us; speedup 1.0000x reference)
//
#include <hip/hip_runtime.h>
#include <stdint.h>

#define TOL 1e-2f
#define WPB 4
// ws layout: [0..128): 8 hashed flag slots (2 u64 each); [192..200): ctl {S, ok};
//            [4096..): z checkpoints, one 2 MB slab per step.
#define WS_CTL_OFF 192
#define WS_Z_OFF   4096

__device__ __forceinline__ float bcastf(float v, int l) {
    return __int_as_float(__builtin_amdgcn_readlane(__float_as_int(v), l));
}

template <int PAT>
__device__ __forceinline__ float swz(float v) {
    return __int_as_float(__builtin_amdgcn_ds_swizzle(__float_as_int(v), PAT));
}
#define SWZ_XOR16 0x401F   // src = lane ^ 16 (within 32-lane half)
#define SWZ_AND15 0x000F   // src = lane & 15 (within 32-lane half)

// MODE 0: run mi steps from z0; store z_k checkpoints; OR per-step (res>=TOL) bits
//         into hashed global flag slots.
// MODE 1: fallback replay (only if ctl[1]==0): run ctl[0] steps, write out.
template <int MODE>
__global__ __launch_bounds__(256) __attribute__((amdgpu_waves_per_eu(1)))
void dys_pass(
    const float* __restrict__ u_nom,     // (B,16)
    const float* __restrict__ Amat,      // (B,32,16)
    const float* __restrict__ bvec,      // (B,32)
    const int*   __restrict__ mi_ptr,
    const int*   __restrict__ ctl,       // {S, stored_ok}
    unsigned long long* __restrict__ flags,
    float*       __restrict__ zstore,
    int zcap,
    float*       __restrict__ out,
    int B)
{
    if (MODE == 1) { if (ctl[1]) return; }   // checkpoint path valid: gather handles out

    const int tid   = threadIdx.x;
    const int lane  = tid & 63;
    const int wib   = tid >> 6;
    const int elem  = blockIdx.x * WPB + wib;
    const int row32 = lane & 31;
    const int col16 = lane & 15;

    __shared__ float ldsT[WPB][32 * 17];
    float* T = ldsT[wib];

    // ---- load A row (dup on upper half), u, b ----
    const float* Ab = Amat + (size_t)elem * 512 + (size_t)row32 * 16;
    float A_row[16];
    {
        float4 a0 = ((const float4*)Ab)[0];
        float4 a1 = ((const float4*)Ab)[1];
        float4 a2 = ((const float4*)Ab)[2];
        float4 a3 = ((const float4*)Ab)[3];
        A_row[0]=a0.x;  A_row[1]=a0.y;  A_row[2]=a0.z;  A_row[3]=a0.w;
        A_row[4]=a1.x;  A_row[5]=a1.y;  A_row[6]=a1.z;  A_row[7]=a1.w;
        A_row[8]=a2.x;  A_row[9]=a2.y;  A_row[10]=a2.z; A_row[11]=a2.w;
        A_row[12]=a3.x; A_row[13]=a3.y; A_row[14]=a3.z; A_row[15]=a3.w;
    }
    if (lane < 32) {
        #pragma unroll
        for (int k = 0; k < 16; ++k) T[row32 * 17 + k] = A_row[k];
    }
    const float un = u_nom[(size_t)elem * 16 + col16];
    const float bv = bvec[(size_t)elem * 32 + row32];

    // W layout per lane (after setup):
    //   lanes 0-31  (i = lane&15): [AtQA_i(16) | AtQ_i(32)]
    //   lanes 32-63 (j = lane-32): [QA_j(16)   | Q_j(32)  ]
    float W[48];

    // ---- N = 2*A*A^T + I: row (lane&31) into W[16..47] on every lane ----
    {
        float A2[16];
        #pragma unroll
        for (int k = 0; k < 16; ++k) A2[k] = A_row[k] + A_row[k];
        #pragma unroll
        for (int j = 0; j < 32; ++j) {
            float acc = (row32 == j) ? 1.f : 0.f;
            #pragma unroll
            for (int k = 0; k < 16; ++k)
                acc = fmaf(A2[k], bcastf(A_row[k], j), acc);
            W[16 + j] = acc;
        }
    }

    // ---- in-place Gauss-Jordan: W[16..47] becomes Q = N^-1 row (lane&31) ----
    #pragma unroll
    for (int p = 0; p < 32; ++p) {
        float piv = bcastf(W[16 + p], p);
        float d = __builtin_amdgcn_rcpf(piv);
        d = d * (2.f - piv * d);                // one Newton step
        float g = W[16 + p] * d;
        g = (row32 == p) ? (1.f - d) : g;
        float negg = -g;
        #pragma unroll
        for (int j = 0; j < 32; ++j) {
            if (j == p) continue;
            float spj = bcastf(W[16 + j], p);   // OLD pivot-row value
            W[16 + j] = fmaf(negg, spj, W[16 + j]);
        }
        W[16 + p] = (row32 == p) ? d : negg;
    }

    // ---- QA row (lane&31) into W[0..15] ----
    #pragma unroll
    for (int k = 0; k < 16; ++k) W[k] = 0.f;
    #pragma unroll
    for (int m = 0; m < 32; ++m) {
        float q = W[16 + m];
        #pragma unroll
        for (int k = 0; k < 16; ++k)
            W[k] = fmaf(q, bcastf(A_row[k], m), W[k]);
    }

    __syncthreads();

    // ---- lanes 0-31: AtQA row i = col16 (A staged in T, QA row broadcasts) ----
    float tq[16];
    #pragma unroll
    for (int k = 0; k < 16; ++k) tq[k] = 0.f;
    #pragma unroll
    for (int m = 0; m < 32; ++m) {
        float a_mi = T[m * 17 + col16];          // A[m][i]
        #pragma unroll
        for (int k = 0; k < 16; ++k)
            tq[k] = fmaf(a_mi, bcastf(W[k], m), tq[k]);   // * QA[m][k]
    }
    __syncthreads();

    if (lane < 32) {
        #pragma unroll
        for (int k = 0; k < 16; ++k) T[row32 * 17 + k] = W[k];   // stage QA rows
    }
    __syncthreads();

    if (lane < 32) {
        #pragma unroll
        for (int m = 0; m < 32; ++m) W[16 + m] = T[m * 17 + col16];  // AtQ[i][m]=QA[m][i]
        #pragma unroll
        for (int k = 0; k < 16; ++k) W[k] = tq[k];                   // AtQA row i
    }

    // ---- fold c = (lanes<32 ? AtQ.b : Q.b) ----
    float cneg;
    {
        float c0 = 0.f, c1 = 0.f;
        #pragma unroll
        for (int m = 0; m < 32; m += 2) {
            c0 = fmaf(W[16 + m], bcastf(bv, m),     c0);
            c1 = fmaf(W[17 + m], bcastf(bv, m + 1), c1);
        }
        cneg = -(c0 + c1);
    }

    const float sgn = (lane >= 16 && lane < 32) ? 1.f : -1.f;

    const int mi = *mi_ptr;
    const int nsteps = (MODE == 0) ? mi : ctl[0];

    float* zp = zstore + (size_t)elem * 64 + lane;
    const size_t zstride = (size_t)B * 64;

    float z = 0.f;
    unsigned long long m0 = 0ull, m1 = 0ull, b0 = 1ull, b1 = 0ull;

    for (int k = 1; k <= nsteps; ++k) {
        float x   = fmaxf(z, 0.f);
        float x16 = swz<SWZ_XOR16>(x);
        float z16 = swz<SWZ_XOR16>(z);
        float t1  = x - x16;
        float s   = t1 - (z - z16) + un;            // lanes 0-15 valid
        float e   = t1 - un;                        // lanes 0-15 valid
        float h   = fmaf(2.f, x, -z);               // lanes 32-63 valid

        float acc0 = cneg, acc1 = 0.f, acc2 = 0.f, acc3 = 0.f;
        #pragma unroll
        for (int m = 0; m < 16; m += 4) {
            acc0 = fmaf(W[m],     bcastf(s, m),     acc0);
            acc1 = fmaf(W[m + 1], bcastf(s, m + 1), acc1);
            acc2 = fmaf(W[m + 2], bcastf(s, m + 2), acc2);
            acc3 = fmaf(W[m + 3], bcastf(s, m + 3), acc3);
        }
        #pragma unroll
        for (int m = 0; m < 32; m += 4) {
            acc0 = fmaf(W[16 + m], bcastf(h, 32 + m), acc0);
            acc1 = fmaf(W[17 + m], bcastf(h, 33 + m), acc1);
            acc2 = fmaf(W[18 + m], bcastf(h, 34 + m), acc2);
            acc3 = fmaf(W[19 + m], bcastf(h, 35 + m), acc3);
        }
        float acc = (acc0 + acc1) + (acc2 + acc3);  // lanes 0-31: At.w ; 32-63: w

        float ee = swz<SWZ_AND15>(e);               // e[lane&15] (lanes 0-31 valid)
        float t  = (lane < 32) ? fmaf(0.5f, ee, acc) : acc;
        float znew = fmaf(sgn, t, x);

        if (MODE == 0) {
            unsigned long long cy = b0 >> 63;
            b0 <<= 1; b1 = (b1 << 1) | cy;          // b = 1 << k (uniform, SALU)
            unsigned long long any = __ballot(fabsf(znew - z) >= TOL);
            if (any) { m0 |= b0; m1 |= b1; }
            if (k <= zcap) { *zp = znew; zp += zstride; }
        }
        z = znew;
    }

    if (MODE == 0) {
        if (lane == 0) {
            int slot = blockIdx.x & 7;
            atomicOr(flags + 2 * slot,     m0);
            atomicOr(flags + 2 * slot + 1, m1);
        }
    } else {
        float z16b = swz<SWZ_XOR16>(z);
        if (lane < 16) out[(size_t)elem * 16 + lane] = z - z16b;
        out[(size_t)B * 16 + (size_t)elem * 64 + lane] = z;
    }
}

// S = (first k in [1,mi) with global residual < TOL) + 1, else mi.
__global__ void dys_reduce(const int* __restrict__ mi_ptr,
                           const unsigned long long* __restrict__ flags,
                           int zcap, int* __restrict__ ctl)
{
    if (threadIdx.x != 0) return;
    unsigned long long m0 = 0ull, m1 = 0ull;
    for (int s = 0; s < 8; ++s) { m0 |= flags[2*s]; m1 |= flags[2*s+1]; }
    int mi = *mi_ptr;
    int S = mi;
    for (int k = 1; k < mi && k < 128; ++k) {
        unsigned long long bit = (k < 64) ? ((m0 >> k) & 1ull)
                                          : ((m1 >> (k - 64)) & 1ull);
        if (!bit) { S = k + 1; break; }
    }
    if (S < 1) S = 1;
    ctl[0] = S;
    ctl[1] = (S <= zcap) ? 1 : 0;
}

__global__ __launch_bounds__(256) void dys_gather(
    const int* __restrict__ ctl, const float* __restrict__ zstore,
    float* __restrict__ out, int B)
{
    if (!ctl[1]) return;
    int tid  = blockIdx.x * 256 + threadIdx.x;
    int lane = tid & 63;
    int elem = tid >> 6;
    int S = ctl[0];
    float z = zstore[(size_t)(S - 1) * B * 64 + (size_t)elem * 64 + lane];
    float z16 = swz<SWZ_XOR16>(z);
    if (lane < 16) out[(size_t)elem * 16 + lane] = z - z16;
    out[(size_t)B * 16 + (size_t)elem * 64 + lane] = z;
}

extern "C" void kernel_launch(void* const* d_in, const int* in_sizes, int n_in,
                              void* d_out, int out_size, void* d_ws, size_t ws_size,
                              hipStream_t stream) {
    (void)n_in; (void)out_size;
    const float* u_nom = (const float*)d_in[0];
    const float* Amat  = (const float*)d_in[1];
    const float* bvec  = (const float*)d_in[2];
    const int*   mi    = (const int*)d_in[3];

    const int B = in_sizes[0] / 16;                  // 8192

    unsigned long long* flags = (unsigned long long*)d_ws;
    int* ctl = (int*)((char*)d_ws + WS_CTL_OFF);
    float* zstore = (float*)((char*)d_ws + WS_Z_OFF);

    const size_t stepBytes = (size_t)B * 64 * sizeof(float);   // 2 MB
    int zcap = 0;
    if (ws_size > WS_Z_OFF + stepBytes)
        zcap = (int)((ws_size - WS_Z_OFF) / stepBytes);
    if (zcap > 127) zcap = 127;                      // masks cover k < 128

    hipMemsetAsync(d_ws, 0, 256, stream);            // flags + ctl

    const int blocks = B / WPB;
    dys_pass<0><<<blocks, 64 * WPB, 0, stream>>>(u_nom, Amat, bvec, mi, ctl,
                                                 flags, zstore, zcap, (float*)d_out, B);
    dys_reduce<<<1, 64, 0, stream>>>(mi, flags, zcap, ctl);
    // Fallback replay (early-exits when checkpoints cover S):
    dys_pass<1><<<blocks, 64 * WPB, 0, stream>>>(u_nom, Amat, bvec, mi, ctl,
                                                 flags, zstore, zcap, (float*)d_out, B);
    // Checkpoint gather (early-exits when fallback ran):
    dys_gather<<<B * 64 / 256, 256, 0, stream>>>(ctl, zstore, (float*)d_out, B);
}

// Round 5
// 285.693 us; speedup vs baseline: 1.0772x; 1.0772x over previous
//
#include <hip/hip_runtime.h>
#include <stdint.h>

#define TOL 1e-2f
#define WPB 4
// ws layout: [0..128): 8 hashed flag slots (2 u64 each); [192..200): ctl {S, ok};
//            [4096..): z checkpoints, one 2 MB slab per step.
#define WS_CTL_OFF 192
#define WS_Z_OFF   4096

__device__ __forceinline__ float bcastf(float v, int l) {
    return __int_as_float(__builtin_amdgcn_readlane(__float_as_int(v), l));
}

template <int PAT>
__device__ __forceinline__ float swz(float v) {
    return __int_as_float(__builtin_amdgcn_ds_swizzle(__float_as_int(v), PAT));
}
#define SWZ_XOR16 0x401F   // src = lane ^ 16

// MODE 0: run mi steps from z0; store z_k checkpoints; OR per-step (res>=TOL) bits
//         into hashed global flag slots.
// MODE 1: fallback replay (only if ctl[1]==0): run ctl[0] steps, write out.
template <int MODE>
__global__ __launch_bounds__(256) __attribute__((amdgpu_waves_per_eu(1)))
void dys_pass(
    const float* __restrict__ u_nom,     // (B,16)
    const float* __restrict__ Amat,      // (B,32,16)
    const float* __restrict__ bvec,      // (B,32)
    const int*   __restrict__ mi_ptr,
    const int*   __restrict__ ctl,       // {S, stored_ok}
    unsigned long long* __restrict__ flags,
    float*       __restrict__ zstore,
    int zcap,
    float*       __restrict__ out,
    int B)
{
    if (MODE == 1) { if (ctl[1]) return; }   // checkpoint path valid: gather handles out

    const int tid   = threadIdx.x;
    const int lane  = tid & 63;
    const int wib   = tid >> 6;
    const int elem  = blockIdx.x * WPB + wib;
    const int row32 = lane & 31;
    const int col16 = lane & 15;

    // Wave-PRIVATE LDS region (544 floats/wave): setup scratch, then p-broadcast buf.
    // No __syncthreads() anywhere: all accesses are same-wave, ordered by lgkmcnt.
    __shared__ __align__(16) float ldsT[WPB][32 * 17];
    float* T = ldsT[wib];

    // ---- load A row (dup on upper half), u, b ----
    const float* Ab = Amat + (size_t)elem * 512 + (size_t)row32 * 16;
    float A_row[16];
    {
        float4 a0 = ((const float4*)Ab)[0];
        float4 a1 = ((const float4*)Ab)[1];
        float4 a2 = ((const float4*)Ab)[2];
        float4 a3 = ((const float4*)Ab)[3];
        A_row[0]=a0.x;  A_row[1]=a0.y;  A_row[2]=a0.z;  A_row[3]=a0.w;
        A_row[4]=a1.x;  A_row[5]=a1.y;  A_row[6]=a1.z;  A_row[7]=a1.w;
        A_row[8]=a2.x;  A_row[9]=a2.y;  A_row[10]=a2.z; A_row[11]=a2.w;
        A_row[12]=a3.x; A_row[13]=a3.y; A_row[14]=a3.z; A_row[15]=a3.w;
    }
    if (lane < 32) {
        #pragma unroll
        for (int k = 0; k < 16; ++k) T[row32 * 17 + k] = A_row[k];
    }
    const float un = u_nom[(size_t)elem * 16 + col16];
    const float bv = bvec[(size_t)elem * 32 + row32];

    // W layout per lane (after setup):
    //   lanes 0-31  (i = lane&15): [AtQA_i(16) | AtQ_i(32)]
    //   lanes 32-63 (j = lane-32): [QA_j(16)   | Q_j(32)  ]
    float W[48];

    // ---- N = 2*A*A^T + I: row (lane&31) into W[16..47] on every lane ----
    {
        float A2[16];
        #pragma unroll
        for (int k = 0; k < 16; ++k) A2[k] = A_row[k] + A_row[k];
        #pragma unroll
        for (int j = 0; j < 32; ++j) {
            float acc = (row32 == j) ? 1.f : 0.f;
            #pragma unroll
            for (int k = 0; k < 16; ++k)
                acc = fmaf(A2[k], bcastf(A_row[k], j), acc);
            W[16 + j] = acc;
        }
    }

    // ---- in-place Gauss-Jordan: W[16..47] becomes Q = N^-1 row (lane&31) ----
    #pragma unroll
    for (int p = 0; p < 32; ++p) {
        float piv = bcastf(W[16 + p], p);
        float d = __builtin_amdgcn_rcpf(piv);
        d = d * (2.f - piv * d);                // one Newton step
        float g = W[16 + p] * d;
        g = (row32 == p) ? (1.f - d) : g;
        float negg = -g;
        #pragma unroll
        for (int j = 0; j < 32; ++j) {
            if (j == p) continue;
            float spj = bcastf(W[16 + j], p);   // OLD pivot-row value
            W[16 + j] = fmaf(negg, spj, W[16 + j]);
        }
        W[16 + p] = (row32 == p) ? d : negg;
    }

    // ---- QA row (lane&31) into W[0..15] ----
    #pragma unroll
    for (int k = 0; k < 16; ++k) W[k] = 0.f;
    #pragma unroll
    for (int m = 0; m < 32; ++m) {
        float q = W[16 + m];
        #pragma unroll
        for (int k = 0; k < 16; ++k)
            W[k] = fmaf(q, bcastf(A_row[k], m), W[k]);
    }

    // ---- lanes 0-31: AtQA row i = col16 (A staged in T, QA row broadcasts) ----
    float tq[16];
    #pragma unroll
    for (int k = 0; k < 16; ++k) tq[k] = 0.f;
    #pragma unroll
    for (int m = 0; m < 32; ++m) {
        float a_mi = T[m * 17 + col16];          // A[m][i]
        #pragma unroll
        for (int k = 0; k < 16; ++k)
            tq[k] = fmaf(a_mi, bcastf(W[k], m), tq[k]);   // * QA[m][k]
    }

    if (lane < 32) {
        #pragma unroll
        for (int k = 0; k < 16; ++k) T[row32 * 17 + k] = W[k];   // stage QA rows
    }
    if (lane < 32) {
        #pragma unroll
        for (int m = 0; m < 32; ++m) W[16 + m] = T[m * 17 + col16];  // AtQ[i][m]=QA[m][i]
        #pragma unroll
        for (int k = 0; k < 16; ++k) W[k] = tq[k];                   // AtQA row i
    }

    // ---- fold c = (lanes<32 ? AtQ.b : Q.b) ----
    float cneg;
    {
        float c0 = 0.f, c1 = 0.f;
        #pragma unroll
        for (int m = 0; m < 32; m += 2) {
            c0 = fmaf(W[16 + m], bcastf(bv, m),     c0);
            c1 = fmaf(W[17 + m], bcastf(bv, m + 1), c1);
        }
        cneg = -(c0 + c1);
    }

    // ---- per-iteration constants ----
    const float sgn  = (lane >= 16 && lane < 32) ? 1.f : -1.f;
    const float sgn0 = (lane & 16) ? -1.f : 1.f;      // for ee on lanes 0-31
    const float nun  = -un;
    // p-buffer slots: s[0..15]<-lanes 0-15; h[0..31]<-lanes 32-63 (slots 16-47);
    // lanes 16-31 dump into slots 48-63.
    const int pslot = (lane < 16) ? lane : ((lane < 32) ? (32 + lane) : (lane - 16));

    const int mi = *mi_ptr;
    const int nsteps = (MODE == 0) ? mi : ctl[0];

    float* zp = zstore + (size_t)elem * 64 + lane;
    const size_t zstride = (size_t)B * 64;

    float z = 0.f;
    unsigned long long m0 = 0ull, m1 = 0ull, b0 = 1ull, b1 = 0ull;

    const float4* Pv = (const float4*)T;

    for (int k = 1; k <= nsteps; ++k) {
        float z16 = swz<SWZ_XOR16>(z);
        float x   = fmaxf(z, 0.f);
        float x16 = fmaxf(z16, 0.f);
        float t1  = x - x16;
        float s   = (t1 - (z - z16)) + un;          // lanes 0-15 valid
        float h   = fmaf(2.f, x, -z);               // lanes 32-63 valid

        T[pslot] = (lane < 32) ? s : h;             // 1 ds_write_b32, 2-way aliased
        float ee = fmaf(sgn0, t1, nun);             // e[lane&15] on lanes 0-31

        float acc0 = cneg, acc1 = 0.f, acc2 = 0.f, acc3 = 0.f;
        #pragma unroll
        for (int q = 0; q < 12; ++q) {
            float4 p = Pv[q];                       // uniform-address broadcast read
            acc0 = fmaf(W[4*q+0], p.x, acc0);
            acc1 = fmaf(W[4*q+1], p.y, acc1);
            acc2 = fmaf(W[4*q+2], p.z, acc2);
            acc3 = fmaf(W[4*q+3], p.w, acc3);
        }
        float acc = (acc0 + acc1) + (acc2 + acc3);  // lanes 0-31: At.w ; 32-63: w

        float t    = (lane < 32) ? fmaf(0.5f, ee, acc) : acc;
        float znew = fmaf(sgn, t, x);

        if (MODE == 0) {
            unsigned long long cy = b0 >> 63;
            b0 <<= 1; b1 = (b1 << 1) | cy;          // b = 1 << k (uniform, SALU)
            unsigned long long any = __ballot(fabsf(znew - z) >= TOL);
            if (any) { m0 |= b0; m1 |= b1; }
            if (k <= zcap) { *zp = znew; zp += zstride; }
        }
        z = znew;
    }

    if (MODE == 0) {
        if (lane == 0) {
            int slot = blockIdx.x & 7;
            atomicOr(flags + 2 * slot,     m0);
            atomicOr(flags + 2 * slot + 1, m1);
        }
    } else {
        float z16b = swz<SWZ_XOR16>(z);
        if (lane < 16) out[(size_t)elem * 16 + lane] = z - z16b;
        out[(size_t)B * 16 + (size_t)elem * 64 + lane] = z;
    }
}

// S = (first k in [1,mi) with global residual < TOL) + 1, else mi.
__global__ void dys_reduce(const int* __restrict__ mi_ptr,
                           const unsigned long long* __restrict__ flags,
                           int zcap, int* __restrict__ ctl)
{
    if (threadIdx.x != 0) return;
    unsigned long long m0 = 0ull, m1 = 0ull;
    for (int s = 0; s < 8; ++s) { m0 |= flags[2*s]; m1 |= flags[2*s+1]; }
    int mi = *mi_ptr;
    int S = mi;
    for (int k = 1; k < mi && k < 128; ++k) {
        unsigned long long bit = (k < 64) ? ((m0 >> k) & 1ull)
                                          : ((m1 >> (k - 64)) & 1ull);
        if (!bit) { S = k + 1; break; }
    }
    if (S < 1) S = 1;
    ctl[0] = S;
    ctl[1] = (S <= zcap) ? 1 : 0;
}

__global__ __launch_bounds__(256) void dys_gather(
    const int* __restrict__ ctl, const float* __restrict__ zstore,
    float* __restrict__ out, int B)
{
    if (!ctl[1]) return;
    int tid  = blockIdx.x * 256 + threadIdx.x;
    int lane = tid & 63;
    int elem = tid >> 6;
    int S = ctl[0];
    float z = zstore[(size_t)(S - 1) * B * 64 + (size_t)elem * 64 + lane];
    float z16 = swz<SWZ_XOR16>(z);
    if (lane < 16) out[(size_t)elem * 16 + lane] = z - z16;
    out[(size_t)B * 16 + (size_t)elem * 64 + lane] = z;
}

extern "C" void kernel_launch(void* const* d_in, const int* in_sizes, int n_in,
                              void* d_out, int out_size, void* d_ws, size_t ws_size,
                              hipStream_t stream) {
    (void)n_in; (void)out_size;
    const float* u_nom = (const float*)d_in[0];
    const float* Amat  = (const float*)d_in[1];
    const float* bvec  = (const float*)d_in[2];
    const int*   mi    = (const int*)d_in[3];

    const int B = in_sizes[0] / 16;                  // 8192

    unsigned long long* flags = (unsigned long long*)d_ws;
    int* ctl = (int*)((char*)d_ws + WS_CTL_OFF);
    float* zstore = (float*)((char*)d_ws + WS_Z_OFF);

    const size_t stepBytes = (size_t)B * 64 * sizeof(float);   // 2 MB
    int zcap = 0;
    if (ws_size > WS_Z_OFF + stepBytes)
        zcap = (int)((ws_size - WS_Z_OFF) / stepBytes);
    if (zcap > 127) zcap = 127;                      // masks cover k < 128

    hipMemsetAsync(d_ws, 0, 256, stream);            // flags + ctl

    const int blocks = B / WPB;
    dys_pass<0><<<blocks, 64 * WPB, 0, stream>>>(u_nom, Amat, bvec, mi, ctl,
                                                 flags, zstore, zcap, (float*)d_out, B);
    dys_reduce<<<1, 64, 0, stream>>>(mi, flags, zcap, ctl);
    // Fallback replay (early-exits when checkpoints cover S):
    dys_pass<1><<<blocks, 64 * WPB, 0, stream>>>(u_nom, Amat, bvec, mi, ctl,
                                                 flags, zstore, zcap, (float*)d_out, B);
    // Checkpoint gather (early-exits when fallback ran):
    dys_gather<<<B * 64 / 256, 256, 0, stream>>>(ctl, zstore, (float*)d_out, B);
}